// Round 13
// baseline (189.714 us; speedup 1.0000x reference)
//
#include <hip/hip_runtime.h>

#define NJ  21
#define FT  6
#define TRS 43   // output tile row stride (floats); odd -> bank-conflict-free
#define TRW 64   // tile rows (was 128): LDS 36.9->25.8KB -> 6 blocks/CU
#define JW  176  // packed per-joint weights: 16 rows x (10w + bias) = 176

// Weight delivery (r12, proven): per joint stage weights into 3 lane-resident
// VGPRs (3x stride-1 ds_read_b32), fetch each with v_readlane -> SGPR ->
// fma scalar operand. LDS pipe ~free, VALU carries fma+readlane.
// r13 change: tile 128->64 rows. r12 was 40% occupancy (4 blk/CU, LDS-capped)
// with VALUBusy 58% -- latency (quat loads, RL->fma deps, barriers) exposed.
// 25.8KB -> 6 blk/CU = 24 waves/CU (75%) to feed the VALU.

__device__ __forceinline__ float RL(float v, int l) {
    return __int_as_float(__builtin_amdgcn_readlane(__float_as_int(v), l));
}
// weight k of joint-block N (k compile-time constant -> single v_readlane)
#define RW(N,k) ((k) < 64 ? RL(wv##N##_0, (k)) : \
                 (k) < 128 ? RL(wv##N##_1, (k)-64) : RL(wv##N##_2, (k)-128))

// hidden row r (weights k = r*11 + 0..9, bias at r*11+10)
#define HROW(N,P,r) const float h##N##_##r = fmaxf( \
  fmaf(RW(N,(r)*11+9), f##P##_5, fmaf(RW(N,(r)*11+8), f##P##_4, \
  fmaf(RW(N,(r)*11+7), f##P##_3, fmaf(RW(N,(r)*11+6), f##P##_2, \
  fmaf(RW(N,(r)*11+5), f##P##_1, fmaf(RW(N,(r)*11+4), f##P##_0, \
  fmaf(RW(N,(r)*11+3), q##N.w,   fmaf(RW(N,(r)*11+2), q##N.z, \
  fmaf(RW(N,(r)*11+1), q##N.y,   fmaf(RW(N,(r)*11+0), q##N.x, \
  RW(N,(r)*11+10))))))))))), 0.0f);

// output row r (weights k = 110 + r*11 + 0..9, bias at +10)
#define FROW(N,r) const float f##N##_##r = fmaxf( \
  fmaf(RW(N,110+(r)*11+9), h##N##_9, fmaf(RW(N,110+(r)*11+8), h##N##_8, \
  fmaf(RW(N,110+(r)*11+7), h##N##_7, fmaf(RW(N,110+(r)*11+6), h##N##_6, \
  fmaf(RW(N,110+(r)*11+5), h##N##_5, fmaf(RW(N,110+(r)*11+4), h##N##_4, \
  fmaf(RW(N,110+(r)*11+3), h##N##_3, fmaf(RW(N,110+(r)*11+2), h##N##_2, \
  fmaf(RW(N,110+(r)*11+1), h##N##_1, fmaf(RW(N,110+(r)*11+0), h##N##_0, \
  RW(N,110+(r)*11+10))))))))))), 0.0f);

#define DO_JOINT(j,P,N) \
  const float4 q##N = qv[j]; \
  const float wv##N##_0 = jw[(j)*JW + lane]; \
  const float wv##N##_1 = jw[(j)*JW + 64 + lane]; \
  const float wv##N##_2 = jw[(j)*JW + 128 + lane]; \
  HROW(N,P,0) HROW(N,P,1) HROW(N,P,2) HROW(N,P,3) HROW(N,P,4) \
  HROW(N,P,5) HROW(N,P,6) HROW(N,P,7) HROW(N,P,8) HROW(N,P,9) \
  FROW(N,0) FROW(N,1) FROW(N,2) FROW(N,3) FROW(N,4) FROW(N,5)

#define PUT6(p, X) { (p)[0]=f##X##_0; (p)[1]=f##X##_1; (p)[2]=f##X##_2; \
                     (p)[3]=f##X##_3; (p)[4]=f##X##_4; (p)[5]=f##X##_5; }

// Quarter flush: wave q PUTs its 64 rows, then ALL threads stream them out.
// PUT banks: lane l -> addr (l*43+c)*4, 43 odd -> conflict-free.
#define QFLUSH(k, q, N0,N1,N2,N3,N4,N5,N6) \
  __syncthreads(); \
  if ((tid >> 6) == (q)) { \
    float* tr_ = tile + (tid & 63) * TRS; \
    PUT6(tr_+0,  N0) PUT6(tr_+6,  N1) PUT6(tr_+12, N2) PUT6(tr_+18, N3) \
    PUT6(tr_+24, N4) PUT6(tr_+30, N5) PUT6(tr_+36, N6) \
  } \
  __syncthreads(); \
  for (int i_ = tid; i_ < TRW*42; i_ += 256) { \
    const int row_ = i_ / 42, col_ = i_ - row_ * 42; \
    out[(size_t)(base + (q)*TRW + row_) * 126 + (k)*42 + col_] = \
        tile[row_ * TRS + col_]; \
  }

#define CHUNK_FLUSH(k, N0,N1,N2,N3,N4,N5,N6) \
  QFLUSH(k, 0, N0,N1,N2,N3,N4,N5,N6) \
  QFLUSH(k, 1, N0,N1,N2,N3,N4,N5,N6) \
  QFLUSH(k, 2, N0,N1,N2,N3,N4,N5,N6) \
  QFLUSH(k, 3, N0,N1,N2,N3,N4,N5,N6)

__global__ __launch_bounds__(256, 4) void se_kernel(
    const float* __restrict__ quat,   // [B, 21, 4]
    const float* __restrict__ W1r,    // [10, 4]
    const float* __restrict__ b1r,    // [10]
    const float* __restrict__ W1,     // [20, 10, 10]
    const float* __restrict__ b1,     // [20, 10]
    const float* __restrict__ W2,     // [21, 6, 10]
    const float* __restrict__ b2,     // [21, 6]
    float*       __restrict__ out,    // [B, 126]
    int B)
{
    __shared__ float jw[NJ * JW];     // 14784 B packed weights
    __shared__ float tile[TRW * TRS]; // 11008 B -> total ~25.8 KB, 6 blk/CU

    const int tid  = threadIdx.x;
    const int lane = tid & 63;
    const int base = blockIdx.x * 256;

    // ---- stage packed weights (joint j block: 110 W1|b1 then 66 W2|b2) ----
    for (int i = tid; i < 20*110; i += 256) {          // joints 1..20, layer 1
        const int j = i / 110, k = i % 110, r = k / 11, c = k % 11;
        jw[(j+1)*JW + k] = (c < 10) ? W1[j*100 + r*10 + c] : b1[j*10 + r];
    }
    for (int i = tid; i < 20*66; i += 256) {           // joints 1..20, layer 2
        const int j = i / 66, k = i % 66, r = k / 11, c = k % 11;
        jw[(j+1)*JW + 110 + k] = (c < 10) ? W2[(j+1)*60 + r*10 + c]
                                          : b2[(j+1)*6 + r];
    }
    if (tid < 50) {                                    // root layer 1: 5/row
        const int r = tid / 5, c = tid % 5;
        jw[tid] = (c < 4) ? W1r[r*4 + c] : b1r[r];
    }
    if (tid < 66) {                                    // root layer 2 at +50
        const int r = tid / 11, c = tid % 11;
        jw[50 + tid] = (c < 10) ? W2[r*10 + c] : b2[r];
    }
    __syncthreads();

    const int bcl = min(base + tid, B - 1);
    const float4* __restrict__ qv =
        reinterpret_cast<const float4*>(quat) + (size_t)bcl * NJ;

    // ---- chunk 0: joints 0..6 ----
    // root: W1r rows are 5 floats (4w+bias at r*5+4); W2 block at +50
    const float4 q0 = qv[0];
    const float wv0_0 = jw[lane];
    const float wv0_1 = jw[64 + lane];
    const float wv0_2 = jw[128 + lane];    // unused (root block = 116), DCE'd
#define H0ROW(r) const float h0_##r = fmaxf( \
    fmaf(RW(0,(r)*5+3), q0.w, fmaf(RW(0,(r)*5+2), q0.z, \
    fmaf(RW(0,(r)*5+1), q0.y, fmaf(RW(0,(r)*5+0), q0.x, RW(0,(r)*5+4))))), 0.0f);
    H0ROW(0) H0ROW(1) H0ROW(2) H0ROW(3) H0ROW(4)
    H0ROW(5) H0ROW(6) H0ROW(7) H0ROW(8) H0ROW(9)
#undef H0ROW
#define F0ROW(r) const float f0_##r = fmaxf( \
    fmaf(RW(0,50+(r)*11+9), h0_9, fmaf(RW(0,50+(r)*11+8), h0_8, \
    fmaf(RW(0,50+(r)*11+7), h0_7, fmaf(RW(0,50+(r)*11+6), h0_6, \
    fmaf(RW(0,50+(r)*11+5), h0_5, fmaf(RW(0,50+(r)*11+4), h0_4, \
    fmaf(RW(0,50+(r)*11+3), h0_3, fmaf(RW(0,50+(r)*11+2), h0_2, \
    fmaf(RW(0,50+(r)*11+1), h0_1, fmaf(RW(0,50+(r)*11+0), h0_0, \
    RW(0,50+(r)*11+10))))))))))), 0.0f);
    F0ROW(0) F0ROW(1) F0ROW(2) F0ROW(3) F0ROW(4) F0ROW(5)
#undef F0ROW

    DO_JOINT(1,0,1)  DO_JOINT(2,0,2)  DO_JOINT(3,0,3)
    DO_JOINT(4,1,4)  DO_JOINT(5,2,5)  DO_JOINT(6,3,6)
    CHUNK_FLUSH(0, 0,1,2,3,4,5,6)

    // ---- chunk 1: joints 7..13 ----
    DO_JOINT(7,4,7)   DO_JOINT(8,5,8)   DO_JOINT(9,6,9)
    DO_JOINT(10,7,10) DO_JOINT(11,8,11)
    DO_JOINT(12,9,12) DO_JOINT(13,9,13)
    CHUNK_FLUSH(1, 7,8,9,10,11,12,13)

    // ---- chunk 2: joints 14..20 ----
    DO_JOINT(14,9,14)  DO_JOINT(15,12,15) DO_JOINT(16,13,16)
    DO_JOINT(17,14,17) DO_JOINT(18,16,18)
    DO_JOINT(19,17,19) DO_JOINT(20,18,20)
    CHUNK_FLUSH(2, 14,15,16,17,18,19,20)
}

extern "C" void kernel_launch(void* const* d_in, const int* in_sizes, int n_in,
                              void* d_out, int out_size, void* d_ws, size_t ws_size,
                              hipStream_t stream) {
    const float* quat = (const float*)d_in[0];
    const float* W1r  = (const float*)d_in[1];
    const float* b1r  = (const float*)d_in[2];
    const float* W1   = (const float*)d_in[3];
    const float* b1   = (const float*)d_in[4];
    const float* W2   = (const float*)d_in[5];
    const float* b2   = (const float*)d_in[6];
    float* out = (float*)d_out;

    const int B = in_sizes[0] / (NJ * 4);
    const int blocks = (B + 255) / 256;
    se_kernel<<<blocks, 256, 0, stream>>>(quat, W1r, b1r, W1, b1, W2, b2, out, B);
}